// Round 7
// baseline (141.098 us; speedup 1.0000x reference)
//
#include <hip/hip_runtime.h>
#include <stdint.h>
#include <stddef.h>

// Problem constants (match reference).
#define Bn 32
#define Tn 512
#define Vn 64
#define Fn 64
#define TT 32   // timesteps per workgroup -> grid = 32 * 16 = 512 blocks

typedef __attribute__((ext_vector_type(8))) short bfx8;  // 8 bf16 (4 VGPRs)
typedef __attribute__((ext_vector_type(4))) float fx4;   // fp32 x4 (indexable)
typedef __attribute__((ext_vector_type(4))) int   ix4;
typedef __attribute__((ext_vector_type(2))) int   ix2;

// fp32 -> bf16, round-to-nearest-even (scalar, setup paths only)
__device__ __forceinline__ short f2bf(float f) {
    union { float f; uint32_t u; } c; c.f = f;
    uint32_t u = c.u;
    return (short)((u + 0x7FFFu + ((u >> 16) & 1u)) >> 16);
}
// pack 2 fp32 -> dword {lo = bf16(a), hi = bf16(b)}, round-half-up.
// 2 int adds + 1 v_perm_b32 (no inline asm).
__device__ __forceinline__ int pkbf2(float a, float b) {
    uint32_t ua = __float_as_uint(a) + 0x8000u;
    uint32_t ub = __float_as_uint(b) + 0x8000u;
    return (int)__builtin_amdgcn_perm(ub, ua, 0x07060302u);
}

// Setup-phase data (wt/ps/dg) dies before Theta frags (tf) are written.
union Shmem {
    struct { float wt[64][65]; float ps[4][64]; float dg[64]; } s;  // 17920 B
    short tf[32][64][8];                                            // 32768 B
};

__global__ __launch_bounds__(256, 2) void gcjk_main(
    const float* __restrict__ x, const float* __restrict__ W,
    const float* __restrict__ Theta, float* __restrict__ out)
{
    __shared__ __align__(16) Shmem sm;
    __shared__ __align__(16) short xt[2][64 * 64];  // Xt[f][u] bf16, XOR-swizzled, dbuf

    const int tid  = threadIdx.x;
    const int lane = tid & 63;
    const int wv   = tid >> 6;
    const int l15  = lane & 15;
    const int gg   = lane >> 4;
    // staging mapping: thread owns a 4x4 patch (u0 = 4*sa, f0 = 4*sc)
    const int sc = tid & 15, sa = tid >> 4;

    const int bid = blockIdx.x;
    const int b   = bid >> 4;
    const int t0  = (bid & 15) * TT;

    // ---- setup: load W[b] into LDS ----
    const float4* W4 = (const float4*)(W + b * (Vn * Vn));
    #pragma unroll
    for (int c = 0; c < 4; ++c) {
        float4 wq = W4[c * 256 + tid];
        int flat = (c * 256 + tid) * 4;
        int i = flat >> 6, j = flat & 63;
        sm.s.wt[i][j+0] = wq.x; sm.s.wt[i][j+1] = wq.y;
        sm.s.wt[i][j+2] = wq.z; sm.s.wt[i][j+3] = wq.w;
    }
    __syncthreads();

    // column sums deg[j] = sum_i W[i][j]
    {
        float s = 0.f;
        #pragma unroll
        for (int r = 0; r < 16; ++r) s += sm.s.wt[wv * 16 + r][lane];
        sm.s.ps[wv][lane] = s;
    }
    __syncthreads();
    if (tid < 64) sm.s.dg[tid] = sm.s.ps[0][tid] + sm.s.ps[1][tid] + sm.s.ps[2][tid] + sm.s.ps[3][tid];
    __syncthreads();

    // ---- A fragments (stage-1 B-operand) in registers ----
    // af[k][s] element e = T_k[u = 32s+8gg+e][v = 16wv+l15]
    bfx8 af[4][2];
    {
        const int v = 16 * wv + l15;
        #pragma unroll
        for (int s = 0; s < 2; ++s) {
            #pragma unroll
            for (int e = 0; e < 8; ++e) {
                int u = 32 * s + 8 * gg + e;
                float wuv = sm.s.wt[u][v];
                float lt  = ((u == v) ? (sm.s.dg[u] - 1.0f) : 0.0f) - wuv;  // D - W - I
                float p0  = (u == v) ? 1.0f : 0.0f;
                float p1  = lt;
                float p2  = 2.0f * lt * p1 - p0;   // elementwise Chebyshev
                float p3  = 2.0f * lt * p2 - p1;
                af[0][s][e] = f2bf(p0);
                af[1][s][e] = f2bf(p1);
                af[2][s][e] = f2bf(p2);
                af[3][s][e] = f2bf(p3);
            }
        }
    }
    __syncthreads();   // wt/ps/dg dead; union becomes tf

    // ---- Theta fragments staged via LDS, then hoisted into REGISTERS ----
    #pragma unroll
    for (int fi = 0; fi < 8; ++fi) {
        int frag = wv * 8 + fi;
        int gt = frag >> 3, k = (frag >> 1) & 3, fh = frag & 1;
        int g  = 16 * gt + l15;
        #pragma unroll
        for (int e = 0; e < 8; ++e) {
            int f = 16 * (2 * fh + (e >> 2)) + 4 * gg + (e & 3);
            sm.tf[frag][lane][e] = f2bf(Theta[(k * Fn + f) * Fn + g]);
        }
    }
    __syncthreads();
    // one-time LDS->reg hoist: 32 frags x 4 VGPR = 128 VGPR, t-invariant
    bfx8 th[32];
    #pragma unroll
    for (int q = 0; q < 32; ++q) th[q] = *(const bfx8*)&sm.tf[q][lane][0];

    // ---- initial staging of tile t0 into xt[0] ----
    const float* xs = x + (size_t)(b * Tn + t0) * (Vn * Fn);
    {
        fx4 xq[4];
        #pragma unroll
        for (int j = 0; j < 4; ++j) xq[j] = *(const fx4*)(xs + (4 * sa + j) * Fn + 4 * sc);
        #pragma unroll
        for (int r = 0; r < 4; ++r) {
            int f = 4 * sc + r;
            ix2 d; d[0] = pkbf2(xq[0][r], xq[1][r]); d[1] = pkbf2(xq[2][r], xq[3][r]);
            int g = sa ^ (f & 15);          // 8B-granule XOR swizzle
            *(ix2*)&xt[0][f * 64 + g * 4] = d;
        }
    }
    __syncthreads();

    // ---- main t loop: dbuf xt, 1 barrier/iter ----
    const int v = 16 * wv + l15;
    for (int ts = 0; ts < TT; ++ts) {
        const int cur = ts & 1;
        const float* xb = xs + (size_t)ts * (Vn * Fn);

        // early-issue: next tile's staging loads (consumed at iter end)
        fx4 xq[4];
        if (ts + 1 < TT) {
            const float* xn = xb + (Vn * Fn);
            #pragma unroll
            for (int j = 0; j < 4; ++j) xq[j] = *(const fx4*)(xn + (4 * sa + j) * Fn + 4 * sc);
        }

        // X fragments from LDS (swizzled b64 pairs)
        const short* xcur = xt[cur];
        bfx8 xf[4][2];
        #pragma unroll
        for (int ft = 0; ft < 4; ++ft) {
            #pragma unroll
            for (int s = 0; s < 2; ++s) {
                int ub = 8 * s + 2 * gg;
                int g0 = ub ^ l15, g1 = (ub + 1) ^ l15;
                ix2 lo = *(const ix2*)&xcur[(16 * ft + l15) * 64 + g0 * 4];
                ix2 hi = *(const ix2*)&xcur[(16 * ft + l15) * 64 + g1 * 4];
                ix4 q; q[0] = lo[0]; q[1] = lo[1]; q[2] = hi[0]; q[3] = hi[1];
                xf[ft][s] = *(bfx8*)&q;
            }
        }

        fx4 oacc[4] = {fx4{0,0,0,0}, fx4{0,0,0,0}, fx4{0,0,0,0}, fx4{0,0,0,0}};
        #pragma unroll
        for (int k = 0; k < 4; ++k) {
            // stage 1: PT_k[f][v] = sum_u Xt[f][u] * T_k[u][v]
            fx4 pacc[4] = {fx4{0,0,0,0}, fx4{0,0,0,0}, fx4{0,0,0,0}, fx4{0,0,0,0}};
            #pragma unroll
            for (int ft = 0; ft < 4; ++ft) {
                pacc[ft] = __builtin_amdgcn_mfma_f32_16x16x32_bf16(xf[ft][0], af[k][0], pacc[ft], 0, 0, 0);
                pacc[ft] = __builtin_amdgcn_mfma_f32_16x16x32_bf16(xf[ft][1], af[k][1], pacc[ft], 0, 0, 0);
            }
            // stage 2: out'[g][v] += Theta'[g][kf] * PT[kf][v]
            // (register repack via perm; Theta operand now in registers)
            #pragma unroll
            for (int fh = 0; fh < 2; ++fh) {
                fx4 pa = pacc[2*fh], pb = pacc[2*fh+1];
                ix4 pq;
                pq[0] = pkbf2(pa[0], pa[1]); pq[1] = pkbf2(pa[2], pa[3]);
                pq[2] = pkbf2(pb[0], pb[1]); pq[3] = pkbf2(pb[2], pb[3]);
                bfx8 pf = *(bfx8*)&pq;
                #pragma unroll
                for (int gt = 0; gt < 4; ++gt) {
                    oacc[gt] = __builtin_amdgcn_mfma_f32_16x16x32_bf16(th[gt*8 + k*2 + fh], pf, oacc[gt], 0, 0, 0);
                }
            }
        }

        // epilogue: relu(out) + sigmoid(x); x loads issued here (late) to keep
        // register peak below 256 during the MFMA body (L1/L3-hot)
        {
            float* ob = out + (size_t)(b * Tn + t0 + ts) * (Vn * Fn);
            fx4 ex[4];
            #pragma unroll
            for (int gt = 0; gt < 4; ++gt)
                ex[gt] = *(const fx4*)(xb + v * Fn + 16 * gt + 4 * gg);
            #pragma unroll
            for (int gt = 0; gt < 4; ++gt) {
                fx4 xv = ex[gt];
                fx4 o  = oacc[gt];
                fx4 r;
                #pragma unroll
                for (int j = 0; j < 4; ++j)
                    r[j] = fmaxf(o[j], 0.f) + __builtin_amdgcn_rcpf(1.f + __expf(-xv[j]));
                *(fx4*)(ob + v * Fn + 16 * gt + 4 * gg) = r;
            }
        }

        // write-late: pack + commit next tile into the other buffer
        if (ts + 1 < TT) {
            #pragma unroll
            for (int r = 0; r < 4; ++r) {
                int f = 4 * sc + r;
                ix2 d; d[0] = pkbf2(xq[0][r], xq[1][r]); d[1] = pkbf2(xq[2][r], xq[3][r]);
                int g = sa ^ (f & 15);
                *(ix2*)&xt[cur ^ 1][f * 64 + g * 4] = d;
            }
        }
        __syncthreads();
    }
}

extern "C" void kernel_launch(void* const* d_in, const int* in_sizes, int n_in,
                              void* d_out, int out_size, void* d_ws, size_t ws_size,
                              hipStream_t stream) {
    (void)in_sizes; (void)n_in; (void)out_size; (void)d_ws; (void)ws_size;
    const float* x  = (const float*)d_in[0];
    const float* W  = (const float*)d_in[1];
    const float* Th = (const float*)d_in[2];
    float* o = (float*)d_out;
    gcjk_main<<<dim3(Bn * (Tn / TT)), dim3(256), 0, stream>>>(x, W, Th, o);
}

// Round 8
// 135.510 us; speedup vs baseline: 1.0412x; 1.0412x over previous
//
#include <hip/hip_runtime.h>
#include <stdint.h>
#include <stddef.h>

// Problem constants (match reference).
#define Bn 32
#define Tn 512
#define Vn 64
#define Fn 64
#define TT 32   // timesteps per block -> grid = 32 * 16 = 512 blocks (2 blocks/CU, no tail)
#define NI 16   // loop iterations; 2 timesteps (one per wave-group) per iteration

typedef __attribute__((ext_vector_type(8))) short bfx8;  // 8 bf16 (4 VGPRs)
typedef __attribute__((ext_vector_type(4))) float fx4;   // fp32 x4 (indexable)
typedef __attribute__((ext_vector_type(4))) int   ix4;
typedef __attribute__((ext_vector_type(2))) int   ix2;

// fp32 -> bf16, round-to-nearest-even (scalar, setup paths only)
__device__ __forceinline__ short f2bf(float f) {
    union { float f; uint32_t u; } c; c.f = f;
    uint32_t u = c.u;
    return (short)((u + 0x7FFFu + ((u >> 16) & 1u)) >> 16);
}
// pack 2 fp32 -> dword {lo = bf16(a), hi = bf16(b)}, round-half-up.
// 2 int adds + 1 v_perm_b32 (no inline asm).
__device__ __forceinline__ int pkbf2(float a, float b) {
    uint32_t ua = __float_as_uint(a) + 0x8000u;
    uint32_t ub = __float_as_uint(b) + 0x8000u;
    return (int)__builtin_amdgcn_perm(ub, ua, 0x07060302u);
}

// Setup-phase data (wt/ps/dg) dies before Theta frags (tf) are written.
union Shmem {
    struct { float wt[64][65]; float ps[8][64]; float dg[64]; } s;  // 18944 B
    short tf[32][64][8];                                            // 32768 B
};

__global__ __launch_bounds__(512, 4) void gcjk_main(
    const float* __restrict__ x, const float* __restrict__ W,
    const float* __restrict__ Theta, float* __restrict__ out)
{
    __shared__ __align__(16) Shmem sm;
    // two independent t-streams (wave-groups), each double-buffered: 4 x 8 KB
    __shared__ __align__(16) short xt[2][2][64 * 64];

    const int tid  = threadIdx.x;
    const int lane = tid & 63;
    const int wid  = tid >> 6;      // 0..7
    const int wv   = wid & 3;       // v-block within group
    const int grp  = wid >> 2;      // t-stream group 0/1
    const int l15  = lane & 15;
    const int gg   = lane >> 4;
    // staging mapping within a group: 256 threads own a 4x4 patch each
    const int gtid = tid & 255;
    const int sc = gtid & 15, sa = gtid >> 4;

    const int bid = blockIdx.x;
    const int b   = bid >> 4;
    const int t0  = (bid & 15) * TT;

    // ---- setup: load W[b] into LDS (512 threads, 2 float4 each) ----
    const float4* W4 = (const float4*)(W + b * (Vn * Vn));
    #pragma unroll
    for (int c = 0; c < 2; ++c) {
        int idx = c * 512 + tid;
        float4 wq = W4[idx];
        int flat = idx * 4;
        int i = flat >> 6, j = flat & 63;
        sm.s.wt[i][j+0] = wq.x; sm.s.wt[i][j+1] = wq.y;
        sm.s.wt[i][j+2] = wq.z; sm.s.wt[i][j+3] = wq.w;
    }
    __syncthreads();

    // column sums deg[j] = sum_i W[i][j] (8 waves x 8 rows)
    {
        float s = 0.f;
        #pragma unroll
        for (int r = 0; r < 8; ++r) s += sm.s.wt[wid * 8 + r][lane];
        sm.s.ps[wid][lane] = s;
    }
    __syncthreads();
    if (tid < 64) {
        float s = 0.f;
        #pragma unroll
        for (int p = 0; p < 8; ++p) s += sm.s.ps[p][tid];
        sm.s.dg[tid] = s;
    }
    __syncthreads();

    // ---- A fragments (stage-1 B-operand) in registers ----
    // af[k][s] element e = T_k[u = 32s+8gg+e][v = 16wv+l15]
    bfx8 af[4][2];
    {
        const int v = 16 * wv + l15;
        #pragma unroll
        for (int s = 0; s < 2; ++s) {
            #pragma unroll
            for (int e = 0; e < 8; ++e) {
                int u = 32 * s + 8 * gg + e;
                float wuv = sm.s.wt[u][v];
                float lt  = ((u == v) ? (sm.s.dg[u] - 1.0f) : 0.0f) - wuv;  // D - W - I
                float p0  = (u == v) ? 1.0f : 0.0f;
                float p1  = lt;
                float p2  = 2.0f * lt * p1 - p0;   // elementwise Chebyshev
                float p3  = 2.0f * lt * p2 - p1;
                af[0][s][e] = f2bf(p0);
                af[1][s][e] = f2bf(p1);
                af[2][s][e] = f2bf(p2);
                af[3][s][e] = f2bf(p3);
            }
        }
    }
    __syncthreads();   // wt/ps/dg dead; union becomes tf

    // ---- Theta fragments (stage-2 A-operand) into LDS (4 frags per wave) ----
    #pragma unroll
    for (int fi = 0; fi < 4; ++fi) {
        int frag = wid * 4 + fi;
        int gt = frag >> 3, k = (frag >> 1) & 3, fh = frag & 1;
        int g  = 16 * gt + l15;
        #pragma unroll
        for (int e = 0; e < 8; ++e) {
            int f = 16 * (2 * fh + (e >> 2)) + 4 * gg + (e & 3);
            sm.tf[frag][lane][e] = f2bf(Theta[(k * Fn + f) * Fn + g]);
        }
    }

    // ---- initial staging: group g stages t0+g into xt[grp][0] ----
    const float* xs = x + (size_t)(b * Tn + t0 + grp) * (Vn * Fn);
    {
        fx4 xq[4];
        #pragma unroll
        for (int j = 0; j < 4; ++j) xq[j] = *(const fx4*)(xs + (4 * sa + j) * Fn + 4 * sc);
        #pragma unroll
        for (int r = 0; r < 4; ++r) {
            int f = 4 * sc + r;
            ix2 d; d[0] = pkbf2(xq[0][r], xq[1][r]); d[1] = pkbf2(xq[2][r], xq[3][r]);
            int g = sa ^ (f & 15);          // 8B-granule XOR swizzle
            *(ix2*)&xt[grp][0][f * 64 + g * 4] = d;
        }
    }
    __syncthreads();

    // ---- main loop: 2 timesteps/iter (one per group), dbuf, 1 barrier/iter ----
    const int v = 16 * wv + l15;
    for (int it = 0; it < NI; ++it) {
        const int cur = it & 1;
        // this group's timestep for this iteration: t = t0 + 2*it + grp
        const float* xb = xs + (size_t)(2 * it) * (Vn * Fn);

        // early-issue: epilogue x re-read (L1/L3-hot) for the CURRENT tile
        fx4 ex[4];
        #pragma unroll
        for (int gt = 0; gt < 4; ++gt)
            ex[gt] = *(const fx4*)(xb + v * Fn + 16 * gt + 4 * gg);

        // early-issue: this group's NEXT tile (t + 2) staging loads
        fx4 xq[4];
        if (it + 1 < NI) {
            const float* xn = xb + 2 * (Vn * Fn);
            #pragma unroll
            for (int j = 0; j < 4; ++j) xq[j] = *(const fx4*)(xn + (4 * sa + j) * Fn + 4 * sc);
        }

        // X fragments from LDS (swizzled b64 pairs)
        const short* xcur = xt[grp][cur];
        bfx8 xf[4][2];
        #pragma unroll
        for (int ft = 0; ft < 4; ++ft) {
            #pragma unroll
            for (int s = 0; s < 2; ++s) {
                int ub = 8 * s + 2 * gg;
                int g0 = ub ^ l15, g1 = (ub + 1) ^ l15;
                ix2 lo = *(const ix2*)&xcur[(16 * ft + l15) * 64 + g0 * 4];
                ix2 hi = *(const ix2*)&xcur[(16 * ft + l15) * 64 + g1 * 4];
                ix4 q; q[0] = lo[0]; q[1] = lo[1]; q[2] = hi[0]; q[3] = hi[1];
                xf[ft][s] = *(bfx8*)&q;
            }
        }

        fx4 oacc[4] = {fx4{0,0,0,0}, fx4{0,0,0,0}, fx4{0,0,0,0}, fx4{0,0,0,0}};
        #pragma unroll
        for (int k = 0; k < 4; ++k) {
            // stage 1: PT_k[f][v] = sum_u Xt[f][u] * T_k[u][v]
            fx4 pacc[4] = {fx4{0,0,0,0}, fx4{0,0,0,0}, fx4{0,0,0,0}, fx4{0,0,0,0}};
            #pragma unroll
            for (int ft = 0; ft < 4; ++ft) {
                pacc[ft] = __builtin_amdgcn_mfma_f32_16x16x32_bf16(xf[ft][0], af[k][0], pacc[ft], 0, 0, 0);
                pacc[ft] = __builtin_amdgcn_mfma_f32_16x16x32_bf16(xf[ft][1], af[k][1], pacc[ft], 0, 0, 0);
            }
            // stage 2: out'[g][v] += Theta'[g][kf] * PT[kf][v] (register repack via perm)
            #pragma unroll
            for (int fh = 0; fh < 2; ++fh) {
                fx4 pa = pacc[2*fh], pb = pacc[2*fh+1];
                ix4 pq;
                pq[0] = pkbf2(pa[0], pa[1]); pq[1] = pkbf2(pa[2], pa[3]);
                pq[2] = pkbf2(pb[0], pb[1]); pq[3] = pkbf2(pb[2], pb[3]);
                bfx8 pf = *(bfx8*)&pq;
                #pragma unroll
                for (int gt = 0; gt < 4; ++gt) {
                    bfx8 th = *(const bfx8*)&sm.tf[gt*8 + k*2 + fh][lane][0];
                    oacc[gt] = __builtin_amdgcn_mfma_f32_16x16x32_bf16(th, pf, oacc[gt], 0, 0, 0);
                }
            }
        }

        // epilogue: relu(out) + sigmoid(x) with the pre-loaded ex
        {
            float* ob = out + (size_t)(b * Tn + t0 + 2 * it + grp) * (Vn * Fn);
            #pragma unroll
            for (int gt = 0; gt < 4; ++gt) {
                fx4 xv = ex[gt];
                fx4 o  = oacc[gt];
                fx4 r;
                #pragma unroll
                for (int j = 0; j < 4; ++j)
                    r[j] = fmaxf(o[j], 0.f) + __builtin_amdgcn_rcpf(1.f + __expf(-xv[j]));
                *(fx4*)(ob + v * Fn + 16 * gt + 4 * gg) = r;
            }
        }

        // write-late: pack + commit this group's next tile into the other buffer
        if (it + 1 < NI) {
            #pragma unroll
            for (int r = 0; r < 4; ++r) {
                int f = 4 * sc + r;
                ix2 d; d[0] = pkbf2(xq[0][r], xq[1][r]); d[1] = pkbf2(xq[2][r], xq[3][r]);
                int g = sa ^ (f & 15);
                *(ix2*)&xt[grp][cur ^ 1][f * 64 + g * 4] = d;
            }
        }
        __syncthreads();
    }
}

extern "C" void kernel_launch(void* const* d_in, const int* in_sizes, int n_in,
                              void* d_out, int out_size, void* d_ws, size_t ws_size,
                              hipStream_t stream) {
    (void)in_sizes; (void)n_in; (void)out_size; (void)d_ws; (void)ws_size;
    const float* x  = (const float*)d_in[0];
    const float* W  = (const float*)d_in[1];
    const float* Th = (const float*)d_in[2];
    float* o = (float*)d_out;
    gcjk_main<<<dim3(Bn * (Tn / TT)), dim3(512), 0, stream>>>(x, W, Th, o);
}

// Round 9
// 120.905 us; speedup vs baseline: 1.1670x; 1.1208x over previous
//
#include <hip/hip_runtime.h>
#include <stdint.h>
#include <stddef.h>

// Problem constants (match reference).
#define Bn 32
#define Tn 512
#define Vn 64
#define Fn 64
#define TT 32   // timesteps per workgroup -> grid = 32 * 16 = 512 blocks

typedef __attribute__((ext_vector_type(8))) short bfx8;  // 8 bf16 (4 VGPRs)
typedef __attribute__((ext_vector_type(4))) float fx4;   // fp32 x4 (indexable)
typedef __attribute__((ext_vector_type(4))) int   ix4;
typedef __attribute__((ext_vector_type(2))) int   ix2;

// fp32 -> bf16, round-to-nearest-even (scalar, setup paths only)
__device__ __forceinline__ short f2bf(float f) {
    union { float f; uint32_t u; } c; c.f = f;
    uint32_t u = c.u;
    return (short)((u + 0x7FFFu + ((u >> 16) & 1u)) >> 16);
}
// pack 2 fp32 -> dword {lo = bf16(a), hi = bf16(b)}, round-half-up.
// 2 int adds + 1 v_perm_b32 (no inline asm).
__device__ __forceinline__ int pkbf2(float a, float b) {
    uint32_t ua = __float_as_uint(a) + 0x8000u;
    uint32_t ub = __float_as_uint(b) + 0x8000u;
    return (int)__builtin_amdgcn_perm(ub, ua, 0x07060302u);
}

// LDS-ordering-only barrier: waits ds ops (lgkmcnt) but lets global STORES
// stay in flight across iterations (avoids __syncthreads' vmcnt(0) drain).
// sched_barrier(0) fences pin LDS ops on the correct side (m152/rule-18).
__device__ __forceinline__ void lds_barrier() {
    __builtin_amdgcn_sched_barrier(0);
    asm volatile("s_waitcnt lgkmcnt(0)" ::: "memory");
    __builtin_amdgcn_s_barrier();
    __builtin_amdgcn_sched_barrier(0);
}

// Setup-phase data (wt/ps/dg) dies before Theta frags (tf) are written.
union Shmem {
    struct { float wt[64][65]; float ps[4][64]; float dg[64]; } s;  // 17920 B
    short tf[32][64][8];                                            // 32768 B
};

__global__ __launch_bounds__(256, 2) void gcjk_main(
    const float* __restrict__ x, const float* __restrict__ W,
    const float* __restrict__ Theta, float* __restrict__ out)
{
    __shared__ __align__(16) Shmem sm;
    __shared__ __align__(16) short xt[2][64 * 64];  // Xt[f][u] bf16, XOR-swizzled, dbuf

    const int tid  = threadIdx.x;
    const int lane = tid & 63;
    const int wv   = tid >> 6;
    const int l15  = lane & 15;
    const int gg   = lane >> 4;
    // staging mapping: thread owns a 4x4 patch (u0 = 4*sa, f0 = 4*sc)
    const int sc = tid & 15, sa = tid >> 4;

    const int bid = blockIdx.x;
    const int b   = bid >> 4;
    const int t0  = (bid & 15) * TT;

    // ---- setup: load W[b] into LDS ----
    const float4* W4 = (const float4*)(W + b * (Vn * Vn));
    #pragma unroll
    for (int c = 0; c < 4; ++c) {
        float4 wq = W4[c * 256 + tid];
        int flat = (c * 256 + tid) * 4;
        int i = flat >> 6, j = flat & 63;
        sm.s.wt[i][j+0] = wq.x; sm.s.wt[i][j+1] = wq.y;
        sm.s.wt[i][j+2] = wq.z; sm.s.wt[i][j+3] = wq.w;
    }
    __syncthreads();

    // column sums deg[j] = sum_i W[i][j]
    {
        float s = 0.f;
        #pragma unroll
        for (int r = 0; r < 16; ++r) s += sm.s.wt[wv * 16 + r][lane];
        sm.s.ps[wv][lane] = s;
    }
    __syncthreads();
    if (tid < 64) sm.s.dg[tid] = sm.s.ps[0][tid] + sm.s.ps[1][tid] + sm.s.ps[2][tid] + sm.s.ps[3][tid];
    __syncthreads();

    // ---- A fragments (stage-1 B-operand) in registers ----
    // af[k][s] element e = T_k[u = 32s+8gg+e][v = 16wv+l15]
    bfx8 af[4][2];
    {
        const int v = 16 * wv + l15;
        #pragma unroll
        for (int s = 0; s < 2; ++s) {
            #pragma unroll
            for (int e = 0; e < 8; ++e) {
                int u = 32 * s + 8 * gg + e;
                float wuv = sm.s.wt[u][v];
                float lt  = ((u == v) ? (sm.s.dg[u] - 1.0f) : 0.0f) - wuv;  // D - W - I
                float p0  = (u == v) ? 1.0f : 0.0f;
                float p1  = lt;
                float p2  = 2.0f * lt * p1 - p0;   // elementwise Chebyshev
                float p3  = 2.0f * lt * p2 - p1;
                af[0][s][e] = f2bf(p0);
                af[1][s][e] = f2bf(p1);
                af[2][s][e] = f2bf(p2);
                af[3][s][e] = f2bf(p3);
            }
        }
    }
    __syncthreads();   // wt/ps/dg dead; union becomes tf

    // ---- Theta fragments (stage-2 A-operand) into LDS ----
    #pragma unroll
    for (int fi = 0; fi < 8; ++fi) {
        int frag = wv * 8 + fi;
        int gt = frag >> 3, k = (frag >> 1) & 3, fh = frag & 1;
        int g  = 16 * gt + l15;
        #pragma unroll
        for (int e = 0; e < 8; ++e) {
            int f = 16 * (2 * fh + (e >> 2)) + 4 * gg + (e & 3);
            sm.tf[frag][lane][e] = f2bf(Theta[(k * Fn + f) * Fn + g]);
        }
    }

    // ---- initial staging of tile t0 into xt[0] ----
    const float* xs = x + (size_t)(b * Tn + t0) * (Vn * Fn);
    {
        fx4 xq[4];
        #pragma unroll
        for (int j = 0; j < 4; ++j) xq[j] = *(const fx4*)(xs + (4 * sa + j) * Fn + 4 * sc);
        #pragma unroll
        for (int r = 0; r < 4; ++r) {
            int f = 4 * sc + r;
            ix2 d; d[0] = pkbf2(xq[0][r], xq[1][r]); d[1] = pkbf2(xq[2][r], xq[3][r]);
            int g = sa ^ (f & 15);          // 8B-granule XOR swizzle
            *(ix2*)&xt[0][f * 64 + g * 4] = d;
        }
    }
    __syncthreads();

    // ---- main t loop: dbuf xt, 1 LDS-only barrier/iter ----
    for (int ts = 0; ts < TT; ++ts) {
        const int cur = ts & 1;
        const float* xb = xs + (size_t)ts * (Vn * Fn);
        const int v = 16 * wv + l15;

        // early-issue: epilogue x re-read (L1/L3-hot) for the CURRENT tile
        fx4 ex[4];
        #pragma unroll
        for (int gt = 0; gt < 4; ++gt)
            ex[gt] = *(const fx4*)(xb + v * Fn + 16 * gt + 4 * gg);

        // early-issue: next tile's staging loads
        fx4 xq[4];
        if (ts + 1 < TT) {
            const float* xn = xb + (Vn * Fn);
            #pragma unroll
            for (int j = 0; j < 4; ++j) xq[j] = *(const fx4*)(xn + (4 * sa + j) * Fn + 4 * sc);
        }

        // X fragments from LDS (swizzled b64 pairs)
        const short* xcur = xt[cur];
        bfx8 xf[4][2];
        #pragma unroll
        for (int ft = 0; ft < 4; ++ft) {
            #pragma unroll
            for (int s = 0; s < 2; ++s) {
                int ub = 8 * s + 2 * gg;
                int g0 = ub ^ l15, g1 = (ub + 1) ^ l15;
                ix2 lo = *(const ix2*)&xcur[(16 * ft + l15) * 64 + g0 * 4];
                ix2 hi = *(const ix2*)&xcur[(16 * ft + l15) * 64 + g1 * 4];
                ix4 q; q[0] = lo[0]; q[1] = lo[1]; q[2] = hi[0]; q[3] = hi[1];
                xf[ft][s] = *(bfx8*)&q;
            }
        }

        fx4 oacc[4] = {fx4{0,0,0,0}, fx4{0,0,0,0}, fx4{0,0,0,0}, fx4{0,0,0,0}};
        #pragma unroll
        for (int k = 0; k < 4; ++k) {
            // stage 1: PT_k[f][v] = sum_u Xt[f][u] * T_k[u][v]
            fx4 pacc[4] = {fx4{0,0,0,0}, fx4{0,0,0,0}, fx4{0,0,0,0}, fx4{0,0,0,0}};
            #pragma unroll
            for (int ft = 0; ft < 4; ++ft) {
                pacc[ft] = __builtin_amdgcn_mfma_f32_16x16x32_bf16(xf[ft][0], af[k][0], pacc[ft], 0, 0, 0);
                pacc[ft] = __builtin_amdgcn_mfma_f32_16x16x32_bf16(xf[ft][1], af[k][1], pacc[ft], 0, 0, 0);
            }
            // stage 2: out'[g][v] += Theta'[g][kf] * PT[kf][v] (register repack via perm)
            #pragma unroll
            for (int fh = 0; fh < 2; ++fh) {
                fx4 pa = pacc[2*fh], pb = pacc[2*fh+1];
                ix4 pq;
                pq[0] = pkbf2(pa[0], pa[1]); pq[1] = pkbf2(pa[2], pa[3]);
                pq[2] = pkbf2(pb[0], pb[1]); pq[3] = pkbf2(pb[2], pb[3]);
                bfx8 pf = *(bfx8*)&pq;
                #pragma unroll
                for (int gt = 0; gt < 4; ++gt) {
                    bfx8 th = *(const bfx8*)&sm.tf[gt*8 + k*2 + fh][lane][0];
                    oacc[gt] = __builtin_amdgcn_mfma_f32_16x16x32_bf16(th, pf, oacc[gt], 0, 0, 0);
                }
            }
        }

        // epilogue: relu(out) + sigmoid(x) with the pre-loaded ex
        {
            float* ob = out + (size_t)(b * Tn + t0 + ts) * (Vn * Fn);
            #pragma unroll
            for (int gt = 0; gt < 4; ++gt) {
                fx4 xv = ex[gt];
                fx4 o  = oacc[gt];
                fx4 r;
                #pragma unroll
                for (int j = 0; j < 4; ++j)
                    r[j] = fmaxf(o[j], 0.f) + __builtin_amdgcn_rcpf(1.f + __expf(-xv[j]));
                *(fx4*)(ob + v * Fn + 16 * gt + 4 * gg) = r;
            }
        }

        // write-late: pack + commit next tile into the other buffer
        if (ts + 1 < TT) {
            #pragma unroll
            for (int r = 0; r < 4; ++r) {
                int f = 4 * sc + r;
                ix2 d; d[0] = pkbf2(xq[0][r], xq[1][r]); d[1] = pkbf2(xq[2][r], xq[3][r]);
                int g = sa ^ (f & 15);
                *(ix2*)&xt[cur ^ 1][f * 64 + g * 4] = d;
            }
        }
        // LDS-only barrier: ds ops drained, global stores stay in flight
        lds_barrier();
    }
}

extern "C" void kernel_launch(void* const* d_in, const int* in_sizes, int n_in,
                              void* d_out, int out_size, void* d_ws, size_t ws_size,
                              hipStream_t stream) {
    (void)in_sizes; (void)n_in; (void)out_size; (void)d_ws; (void)ws_size;
    const float* x  = (const float*)d_in[0];
    const float* W  = (const float*)d_in[1];
    const float* Th = (const float*)d_in[2];
    float* o = (float*)d_out;
    gcjk_main<<<dim3(Bn * (Tn / TT)), dim3(256), 0, stream>>>(x, W, Th, o);
}